// Round 1
// baseline (864.255 us; speedup 1.0000x reference)
//
#include <hip/hip_runtime.h>
#include <math.h>

// ---------------------------------------------------------------------------
// R-GCN (basis decomposition, B=2), 2 layers.
//   Layer: hb[n,b,:] = h[n,:] @ basis[b]          (dense, grid.y = 1,2)
//          agg[n,:]  = h[n,:] @ loop_w + bias     (dense, grid.y = 0)
//          agg[dst]  += sum_b comp[et,b]*hb[src,b,:]   (edge, atomics)
//          h' = act(agg)
// ---------------------------------------------------------------------------

template<int K>
__global__ __launch_bounds__(256) void rgcn_dense(
    const float* __restrict__ x,      // [nNodes][K]
    const float* __restrict__ loopw,  // [K][64]
    const float* __restrict__ basis,  // [2][K][64]
    const float* __restrict__ bias,   // [64]
    float* __restrict__ agg,          // [nNodes][64]   (g==0 writes here)
    float* __restrict__ hb,           // [nNodes][2][64] (g==1,2 write here)
    int nNodes)
{
    __shared__ float WT[64][K + 4];   // transposed weights, +4 pad for banks
    const int g = blockIdx.y;
    const float* __restrict__ W =
        (g == 0) ? loopw : (basis + (size_t)(g - 1) * K * 64);

    // stage W transposed: coalesced global reads
    for (int idx = threadIdx.x; idx < K * 64; idx += 256) {
        int d = idx >> 6, j = idx & 63;
        WT[j][d] = W[idx];
    }
    __syncthreads();

    const int lane = threadIdx.x & 63;
    const int wid  = threadIdx.x >> 6;
    const int nTiles = (nNodes + 3) >> 2;
    const int waveStride = gridDim.x * 4;
    const float bj = (g == 0) ? bias[lane] : 0.0f;
    const float4* __restrict__ wrow =
        reinterpret_cast<const float4*>(&WT[lane][0]);

    for (int tile = blockIdx.x * 4 + wid; tile < nTiles; tile += waveStride) {
        const int n0 = tile * 4;
        if (n0 + 3 < nNodes) {
            const float4* __restrict__ xr0 =
                reinterpret_cast<const float4*>(x + (size_t)n0 * K);
            const float4* __restrict__ xr1 = xr0 + (K / 4);
            const float4* __restrict__ xr2 = xr0 + 2 * (K / 4);
            const float4* __restrict__ xr3 = xr0 + 3 * (K / 4);
            float a0 = 0.f, a1 = 0.f, a2 = 0.f, a3 = 0.f;
            #pragma unroll 8
            for (int d4 = 0; d4 < K / 4; ++d4) {
                const float4 w  = wrow[d4];
                const float4 v0 = xr0[d4];
                const float4 v1 = xr1[d4];
                const float4 v2 = xr2[d4];
                const float4 v3 = xr3[d4];
                a0 += w.x * v0.x + w.y * v0.y + w.z * v0.z + w.w * v0.w;
                a1 += w.x * v1.x + w.y * v1.y + w.z * v1.z + w.w * v1.w;
                a2 += w.x * v2.x + w.y * v2.y + w.z * v2.z + w.w * v2.w;
                a3 += w.x * v3.x + w.y * v3.y + w.z * v3.z + w.w * v3.w;
            }
            if (g == 0) {
                agg[(size_t)(n0 + 0) * 64 + lane] = a0 + bj;
                agg[(size_t)(n0 + 1) * 64 + lane] = a1 + bj;
                agg[(size_t)(n0 + 2) * 64 + lane] = a2 + bj;
                agg[(size_t)(n0 + 3) * 64 + lane] = a3 + bj;
            } else {
                const size_t co = (size_t)(g - 1) * 64 + lane;
                hb[(size_t)(n0 + 0) * 128 + co] = a0;
                hb[(size_t)(n0 + 1) * 128 + co] = a1;
                hb[(size_t)(n0 + 2) * 128 + co] = a2;
                hb[(size_t)(n0 + 3) * 128 + co] = a3;
            }
        } else {
            for (int n = n0; n < nNodes; ++n) {
                float a = 0.f;
                for (int d = 0; d < K; ++d)
                    a += WT[lane][d] * x[(size_t)n * K + d];
                if (g == 0) agg[(size_t)n * 64 + lane] = a + bj;
                else        hb[(size_t)n * 128 + (size_t)(g - 1) * 64 + lane] = a;
            }
        }
    }
}

__global__ __launch_bounds__(256) void rgcn_edge(
    const float* __restrict__ hb,   // [N][2][64]
    const float* __restrict__ comp, // [R][2]
    const int* __restrict__ src,
    const int* __restrict__ dst,
    const int* __restrict__ et,
    float* __restrict__ agg,        // [N][64]
    int nEdges)
{
    const int lane = threadIdx.x & 63;
    const int wid = (blockIdx.x * 256 + threadIdx.x) >> 6;
    const int stride = gridDim.x * 4;
    for (int e = wid; e < nEdges; e += stride) {
        const int s = src[e];
        const int d = dst[e];
        const int t = et[e];
        const float c0 = comp[2 * t];
        const float c1 = comp[2 * t + 1];
        const float* __restrict__ row = hb + (size_t)s * 128;
        const float v = c0 * row[lane] + c1 * row[64 + lane];
        atomicAdd(agg + (size_t)d * 64 + lane, v);
    }
}

__global__ __launch_bounds__(256) void act_tanh4(float* __restrict__ a, int n4)
{
    int i = blockIdx.x * 256 + threadIdx.x;
    const int stride = gridDim.x * 256;
    float4* __restrict__ p = reinterpret_cast<float4*>(a);
    for (; i < n4; i += stride) {
        float4 v = p[i];
        v.x = tanhf(v.x); v.y = tanhf(v.y);
        v.z = tanhf(v.z); v.w = tanhf(v.w);
        p[i] = v;
    }
}

__global__ __launch_bounds__(256) void act_relu4(float* __restrict__ a, int n4)
{
    int i = blockIdx.x * 256 + threadIdx.x;
    const int stride = gridDim.x * 256;
    float4* __restrict__ p = reinterpret_cast<float4*>(a);
    for (; i < n4; i += stride) {
        float4 v = p[i];
        v.x = fmaxf(v.x, 0.f); v.y = fmaxf(v.y, 0.f);
        v.z = fmaxf(v.z, 0.f); v.w = fmaxf(v.w, 0.f);
        p[i] = v;
    }
}

extern "C" void kernel_launch(void* const* d_in, const int* in_sizes, int n_in,
                              void* d_out, int out_size, void* d_ws, size_t ws_size,
                              hipStream_t stream)
{
    const float* node_emb = (const float*)d_in[0];   // [N][128]
    const float* basis1   = (const float*)d_in[1];   // [2][128][64]
    const float* comp1    = (const float*)d_in[2];   // [R][2]
    const float* loop_w1  = (const float*)d_in[3];   // [128][64]
    const float* bias1    = (const float*)d_in[4];   // [64]
    const float* basis2   = (const float*)d_in[5];   // [2][64][64]
    const float* comp2    = (const float*)d_in[6];   // [R][2]
    const float* loop_w2  = (const float*)d_in[7];   // [64][64]
    const float* bias2    = (const float*)d_in[8];   // [64]
    const int*   src      = (const int*)d_in[9];     // [E]
    const int*   dst      = (const int*)d_in[10];    // [E]
    const int*   et       = (const int*)d_in[11];    // [E]

    const int N = in_sizes[0] / 128;
    const int E = in_sizes[9];

    float* out  = (float*)d_out;                 // [N][64] (also layer-2 agg)
    float* hb   = (float*)d_ws;                  // [N][2][64], reused per layer
    float* agg1 = hb + (size_t)N * 128;          // [N][64] -> h after tanh

    const dim3 dgrid(512, 3, 1);

    // ---- layer 1 ----
    rgcn_dense<128><<<dgrid, 256, 0, stream>>>(node_emb, loop_w1, basis1, bias1,
                                               agg1, hb, N);
    rgcn_edge<<<2048, 256, 0, stream>>>(hb, comp1, src, dst, et, agg1, E);
    act_tanh4<<<1024, 256, 0, stream>>>(agg1, (N * 64) / 4);

    // ---- layer 2 ----
    rgcn_dense<64><<<dgrid, 256, 0, stream>>>(agg1, loop_w2, basis2, bias2,
                                              out, hb, N);
    rgcn_edge<<<2048, 256, 0, stream>>>(hb, comp2, src, dst, et, out, E);
    act_relu4<<<1024, 256, 0, stream>>>(out, (N * 64) / 4);
}